// Round 2
// baseline (908.525 us; speedup 1.0000x reference)
//
#include <hip/hip_runtime.h>
#include <hip/hip_bf16.h>

#define T_TOK 4096
#define HDIM  1024
#define FDIM  4096
#define NEXP  8
#define CAP   4096
#define MAXWL 128
#define NT1MAX 40                 // max 256-row tiles: sum ceil(M_e/256) <= 39
#define OBR   (2 * T_TOK + 128)   // compact rows incl. padding

typedef __attribute__((ext_vector_type(8))) short short8;
typedef __attribute__((ext_vector_type(4))) float floatx4;
typedef __attribute__((ext_vector_type(4))) float float4v;
typedef __attribute__((ext_vector_type(4))) unsigned short ushort4v;

// raw barrier: NO implicit vmcnt/lgkmcnt drain (that drain is the m97 ~20% stall).
#define BAR() do { asm volatile("" ::: "memory"); __builtin_amdgcn_s_barrier(); asm volatile("" ::: "memory"); } while (0)
#define VMW6() asm volatile("s_waitcnt vmcnt(6)" ::: "memory")
#define VMW0() asm volatile("s_waitcnt vmcnt(0)" ::: "memory")

__device__ __forceinline__ unsigned short f2bf(float f) {
    union { float f; unsigned int u; } v; v.f = f;
    unsigned int u = v.u;
    u += 0x7fffu + ((u >> 16) & 1u);   // round-to-nearest-even
    return (unsigned short)(u >> 16);
}

__device__ __forceinline__ void gl2lds16(const void* g, void* l) {
    __builtin_amdgcn_global_load_lds(
        (const __attribute__((address_space(1))) unsigned int*)g,
        (__attribute__((address_space(3))) unsigned int*)l,
        16, 0, 0);
}

// ---------------- transpose + cast: src [R][C] fp32 -> dst [C][R] bf16, 64x64 tiles ----------------
__global__ void k_transpose_cast(const float* __restrict__ src, unsigned short* __restrict__ dst,
                                 int R, int C) {
    __shared__ float tile[64][65];
    size_t base = (size_t)blockIdx.z * (size_t)R * (size_t)C;
    int c0 = blockIdx.x * 64, r0 = blockIdx.y * 64;
    int lx = threadIdx.x & 15, ly = threadIdx.x >> 4;
#pragma unroll
    for (int i = 0; i < 4; ++i) {
        int rr = i * 16 + ly;
        float4v v = *(const float4v*)(src + base + (size_t)(r0 + rr) * C + c0 + lx * 4);
        tile[rr][lx * 4 + 0] = v[0]; tile[rr][lx * 4 + 1] = v[1];
        tile[rr][lx * 4 + 2] = v[2]; tile[rr][lx * 4 + 3] = v[3];
    }
    __syncthreads();
#pragma unroll
    for (int i = 0; i < 4; ++i) {
        int cc = i * 16 + ly;
        ushort4v o = { f2bf(tile[lx * 4 + 0][cc]), f2bf(tile[lx * 4 + 1][cc]),
                       f2bf(tile[lx * 4 + 2][cc]), f2bf(tile[lx * 4 + 3][cc]) };
        *(ushort4v*)(dst + base + (size_t)(c0 + cc) * R + r0 + lx * 4) = o;
    }
}

// ---------------- router (+ x cast): logits, softmax, top-2, lists, per-token slots ----------------
__global__ void k_router(const float* __restrict__ x, const float* __restrict__ wgate,
                         unsigned short* __restrict__ xb,
                         int* __restrict__ counts, int* __restrict__ ltok,
                         float* __restrict__ lwt, int* __restrict__ tslot) {
    int lane = threadIdx.x & 63;
    int tok = blockIdx.x * 4 + (threadIdx.x >> 6);
    const float* xr = x + (size_t)tok * HDIM;
    unsigned short* xbr = xb + (size_t)tok * HDIM;
    float acc[NEXP];
#pragma unroll
    for (int e = 0; e < NEXP; ++e) acc[e] = 0.f;
    for (int it = 0; it < HDIM / 256; ++it) {
        int h0 = it * 256 + lane * 4;
        float4v xv = *(const float4v*)(xr + h0);
        ushort4v xo = { f2bf(xv[0]), f2bf(xv[1]), f2bf(xv[2]), f2bf(xv[3]) };
        *(ushort4v*)(xbr + h0) = xo;
#pragma unroll
        for (int j = 0; j < 4; ++j) {
            float4v w0 = *(const float4v*)(wgate + (size_t)(h0 + j) * NEXP);
            float4v w1 = *(const float4v*)(wgate + (size_t)(h0 + j) * NEXP + 4);
            float xs = xv[j];
            acc[0] += xs * w0[0]; acc[1] += xs * w0[1];
            acc[2] += xs * w0[2]; acc[3] += xs * w0[3];
            acc[4] += xs * w1[0]; acc[5] += xs * w1[1];
            acc[6] += xs * w1[2]; acc[7] += xs * w1[3];
        }
    }
#pragma unroll
    for (int off = 32; off >= 1; off >>= 1)
#pragma unroll
        for (int e = 0; e < NEXP; ++e)
            acc[e] += __shfl_xor(acc[e], off, 64);
    if (lane == 0) {
        float m = acc[0];
#pragma unroll
        for (int e = 1; e < NEXP; ++e) m = fmaxf(m, acc[e]);
        float p[NEXP], s = 0.f;
#pragma unroll
        for (int e = 0; e < NEXP; ++e) { p[e] = __expf(acc[e] - m); s += p[e]; }
        float inv = 1.f / s;
#pragma unroll
        for (int e = 0; e < NEXP; ++e) p[e] *= inv;
        int e0 = 0; float b0 = p[0];
#pragma unroll
        for (int e = 1; e < NEXP; ++e) if (p[e] > b0) { b0 = p[e]; e0 = e; }
        int e1 = -1; float b1 = -1.f;
#pragma unroll
        for (int e = 0; e < NEXP; ++e) if (e != e0 && p[e] > b1) { b1 = p[e]; e1 = e; }
        int p0 = atomicAdd(&counts[e0], 1);
        ltok[e0 * CAP + p0] = tok; lwt[e0 * CAP + p0] = b0;
        int p1 = atomicAdd(&counts[e1], 1);
        ltok[e1 * CAP + p1] = tok; lwt[e1 * CAP + p1] = b1;
        tslot[tok * 2]     = (e0 << 16) | p0;
        tslot[tok * 2 + 1] = (e1 << 16) | p1;
    }
}

// prefix sums + compact worklists: wl = 128-row tiles (gemm2), wl1 = 256-row tiles (gemm1)
__global__ void k_prefix(const int* __restrict__ counts, int* __restrict__ offs,
                         int* __restrict__ wl, int* __restrict__ nwl,
                         int* __restrict__ wl1, int* __restrict__ nwl1) {
    if (threadIdx.x == 0) {
        int s = 0;
#pragma unroll
        for (int e = 0; e < NEXP; ++e) { offs[e] = s; s += counts[e]; }
        int n = 0;
        for (int e = 0; e < NEXP; ++e)
            for (int r = 0; r * 128 < counts[e] && n < MAXWL; ++r)
                wl[n++] = (e << 8) | r;
        nwl[0] = n;
        int n1 = 0;
        for (int e = 0; e < NEXP; ++e)
            for (int r = 0; r * 256 < counts[e] && n1 < 64; ++r)
                wl1[n1++] = (e << 8) | r;
        nwl1[0] = n1;
    }
}

// ---------------- GEMM1 v3: h = silu(x@Wg) * (x@Wu) ----------------
// BM=256 rows x (64 gate + 64 up) cols, BK=64. 512 threads / 8 waves (4M x 2N).
// Triple-buffered LDS (prefetch distance 2), counted vmcnt(6), raw barriers,
// XOR chunk swizzle via pre-swizzled gl2lds SOURCE + swizzled ds_read.
// v3 fix: K-loop FULLY UNROLLED so buffer indices are compile-time constants ->
// compiler can disambiguate ds_read vs in-flight global_load_lds and emit counted
// waits instead of conservative vmcnt(0) drains (the v2 regression).
__global__ __launch_bounds__(512, 2)
void k_gemm1(const unsigned short* __restrict__ xb,    // [T][H] bf16
             const unsigned short* __restrict__ wgt,   // [E][F][H] bf16
             const unsigned short* __restrict__ wut,   // [E][F][H]
             const int* __restrict__ counts, const int* __restrict__ offs,
             const int* __restrict__ ltok,
             const int* __restrict__ wl1, const int* __restrict__ nwl1,
             unsigned short* __restrict__ hbuf)        // [OBR][F] bf16
{
    if ((int)blockIdx.y >= nwl1[0]) return;
    const int wle = wl1[blockIdx.y];
    const int e = wle >> 8, rowtile = wle & 255;
    const int M = counts[e];
    const int ftile = blockIdx.x;  // 0..63

    __shared__ __align__(16) unsigned short lA[3][256 * 64];   // 3 x 32 KB
    __shared__ __align__(16) unsigned short lBg[3][64 * 64];   // 3 x 8 KB
    __shared__ __align__(16) unsigned short lBu[3][64 * 64];   // 3 x 8 KB
    __shared__ int stok[256];

    const int t = threadIdx.x;
    const int wave = t >> 6, lane = t & 63;
    const int wm = wave >> 1, wn = wave & 1;    // 4M x 2N wave grid
    const int fr = lane & 15, kg = lane >> 4;
    const int fr7 = fr & 7;
    const int w8 = wave * 8;                    // staging: 8 rows per wave per round
    const int lr = lane >> 3, lc = lane & 7;    // staging lane -> (row, chunk)
    const int swz = (lc ^ lr) * 8;              // pre-swizzled global chunk (shorts)

    if (t < 256) {
        int i = rowtile * 256 + t;
        stok[t] = (i < M) ? ltok[e * CAP + i] : ltok[e * CAP];
    }
    __syncthreads();

    // per-thread staging source pointers (advance 64 shorts = one K-tile per stage)
    const unsigned short* pa0 = xb + (size_t)stok[  0 + w8 + lr] * HDIM + swz;
    const unsigned short* pa1 = xb + (size_t)stok[ 64 + w8 + lr] * HDIM + swz;
    const unsigned short* pa2 = xb + (size_t)stok[128 + w8 + lr] * HDIM + swz;
    const unsigned short* pa3 = xb + (size_t)stok[192 + w8 + lr] * HDIM + swz;
    const size_t wrow = (size_t)(e * FDIM + ftile * 64 + w8 + lr) * HDIM + swz;
    const unsigned short* pg = wgt + wrow;
    const unsigned short* pu = wut + wrow;

    // ds_read offsets (shorts). row stride 64 shorts; chunk = (ks*4+kg) ^ (row&7).
    int ar[4], br[2];
#pragma unroll
    for (int mi = 0; mi < 4; ++mi) ar[mi] = (wm * 64 + mi * 16 + fr) * 64;
#pragma unroll
    for (int ni = 0; ni < 2; ++ni) br[ni] = (wn * 32 + ni * 16 + fr) * 64;
    const int cs0 = ((0 + kg) ^ fr7) * 8;
    const int cs1 = ((4 + kg) ^ fr7) * 8;

    floatx4 accg[4][2], accu[4][2];
#pragma unroll
    for (int mi = 0; mi < 4; ++mi)
#pragma unroll
        for (int ni = 0; ni < 2; ++ni) {
            floatx4 z = {0.f, 0.f, 0.f, 0.f};
            accg[mi][ni] = z; accu[mi][ni] = z;
        }

    auto stage_tile = [&](int b) {   // 6 gl2lds: full K-tile (A 32KB + Bg 8KB + Bu 8KB)
        unsigned short* sA = &lA[b][0];
        gl2lds16(pa0, sA + (  0 + w8) * 64); pa0 += 64;
        gl2lds16(pa1, sA + ( 64 + w8) * 64); pa1 += 64;
        gl2lds16(pa2, sA + (128 + w8) * 64); pa2 += 64;
        gl2lds16(pa3, sA + (192 + w8) * 64); pa3 += 64;
        gl2lds16(pg, &lBg[b][w8 * 64]); pg += 64;
        gl2lds16(pu, &lBu[b][w8 * 64]); pu += 64;
    };

    auto do_tile = [&](int cur, int stb, bool dostage) {
        const unsigned short* cA = &lA[cur][0];
        const unsigned short* cG = &lBg[cur][0];
        const unsigned short* cU = &lBu[cur][0];
        unsigned short* sA = &lA[stb][0];
        short8 a[4], g[2], u[2];
        // ---------- phase ks=0: 8 ds_read_b128 + 3 prefetch, then 16 MFMA ----------
#pragma unroll
        for (int mi = 0; mi < 4; ++mi) a[mi] = *(const short8*)(cA + ar[mi] + cs0);
#pragma unroll
        for (int ni = 0; ni < 2; ++ni) {
            g[ni] = *(const short8*)(cG + br[ni] + cs0);
            u[ni] = *(const short8*)(cU + br[ni] + cs0);
        }
        if (dostage) {
            gl2lds16(pa0, sA + (  0 + w8) * 64); pa0 += 64;
            gl2lds16(pa1, sA + ( 64 + w8) * 64); pa1 += 64;
            gl2lds16(pg, &lBg[stb][w8 * 64]); pg += 64;
        }
        BAR();
        __builtin_amdgcn_s_setprio(1);
#pragma unroll
        for (int mi = 0; mi < 4; ++mi)
#pragma unroll
            for (int ni = 0; ni < 2; ++ni)
                accg[mi][ni] = __builtin_amdgcn_mfma_f32_16x16x32_bf16(a[mi], g[ni], accg[mi][ni], 0, 0, 0);
#pragma unroll
        for (int mi = 0; mi < 4; ++mi)
#pragma unroll
            for (int ni = 0; ni < 2; ++ni)
                accu[mi][ni] = __builtin_amdgcn_mfma_f32_16x16x32_bf16(a[mi], u[ni], accu[mi][ni], 0, 0, 0);
        __builtin_amdgcn_s_setprio(0);
        BAR();
        // ---------- phase ks=1 ----------
#pragma unroll
        for (int mi = 0; mi < 4; ++mi) a[mi] = *(const short8*)(cA + ar[mi] + cs1);
#pragma unroll
        for (int ni = 0; ni < 2; ++ni) {
            g[ni] = *(const short8*)(cG + br[ni] + cs1);
            u[ni] = *(const short8*)(cU + br[ni] + cs1);
        }
        if (dostage) {
            gl2lds16(pa2, sA + (128 + w8) * 64); pa2 += 64;
            gl2lds16(pa3, sA + (192 + w8) * 64); pa3 += 64;
            gl2lds16(pu, &lBu[stb][w8 * 64]); pu += 64;
        }
        BAR();
        __builtin_amdgcn_s_setprio(1);
#pragma unroll
        for (int mi = 0; mi < 4; ++mi)
#pragma unroll
            for (int ni = 0; ni < 2; ++ni)
                accg[mi][ni] = __builtin_amdgcn_mfma_f32_16x16x32_bf16(a[mi], g[ni], accg[mi][ni], 0, 0, 0);
#pragma unroll
        for (int mi = 0; mi < 4; ++mi)
#pragma unroll
            for (int ni = 0; ni < 2; ++ni)
                accu[mi][ni] = __builtin_amdgcn_mfma_f32_16x16x32_bf16(a[mi], u[ni], accu[mi][ni], 0, 0, 0);
        __builtin_amdgcn_s_setprio(0);
        // boundary vmcnt + barrier issued by caller
    };

    // prologue: stage tiles 0,1; wait tile0 (leave tile1's 6 loads in flight)
    stage_tile(0);
    stage_tile(1);
    VMW6();
    BAR();

    // K = 1024 = 16 x BK64. FULLY UNROLLED: cur/stb are compile-time constants,
    // so every LDS base is a static offset (enables precise compiler waitcnts).
#pragma unroll
    for (int kt = 0; kt < 16; ++kt) {
        const int cur = kt % 3;
        const int stb = (kt + 2) % 3;
        do_tile(cur, stb, kt < 14);
        // in flight: tile kt+1 (6, oldest) + tile kt+2 (6, new) -> drain oldest 6
        if (kt < 14) { VMW6(); } else { VMW0(); }
        BAR();
    }

    // epilogue: silu(g)*u -> bf16 hbuf
    const int hrow0 = offs[e] + rowtile * 256;
#pragma unroll
    for (int mi = 0; mi < 4; ++mi)
#pragma unroll
        for (int ni = 0; ni < 2; ++ni) {
            int c = ftile * 64 + wn * 32 + ni * 16 + fr;
#pragma unroll
            for (int r = 0; r < 4; ++r) {
                int rr = wm * 64 + mi * 16 + kg * 4 + r;
                if (rowtile * 256 + rr < M) {
                    float gv = accg[mi][ni][r];
                    float val = (gv / (1.f + __expf(-gv))) * accu[mi][ni][r];
                    hbuf[(size_t)(hrow0 + rr) * FDIM + c] = f2bf(val);
                }
            }
        }
}

// ---------------- GEMM2: obuf[khalf][row] = w * (h @ Wd^T), split-K=2, plain stores ----------------
__global__ __launch_bounds__(256, 2)
void k_gemm2(const unsigned short* __restrict__ hbuf,  // [OBR][F] bf16
             const unsigned short* __restrict__ wdt,   // [E][H][F] bf16
             const int* __restrict__ counts, const int* __restrict__ offs,
             const float* __restrict__ lwt,
             const int* __restrict__ wl, const int* __restrict__ nwl,
             float* __restrict__ obuf)                 // [2][OBR][H] fp32
{
    if ((int)blockIdx.y >= nwl[0]) return;
    const int w = wl[blockIdx.y];
    const int e = w >> 8, rowtile = w & 255;
    const int M = counts[e];
    const int htile = blockIdx.x;  // 0..7
    const int khalf = blockIdx.z;  // 0..1

    __shared__ __align__(16) unsigned short lA[128 * 32];
    __shared__ __align__(16) unsigned short lB[128 * 32];
    __shared__ float swt[128];

    const int t = threadIdx.x;
    const int wave = t >> 6, lane = t & 63;

    if (t < 128) {
        int i = rowtile * 128 + t;
        swt[t] = (i < M) ? lwt[e * CAP + i] : 0.f;
    }

    const int row0 = offs[e] + rowtile * 128;
    const int r0 = t >> 2, k8 = t & 3;
    const int kofs = khalf * (FDIM / 2);
    const unsigned short* pA0 = hbuf + (size_t)(row0 + r0) * FDIM + kofs + k8 * 8;
    const unsigned short* pA1 = hbuf + (size_t)(row0 + 64 + r0) * FDIM + kofs + k8 * 8;
    const size_t wb = (size_t)e * HDIM * FDIM + (size_t)(htile * 128) * FDIM;
    const unsigned short* pB0 = wdt + wb + (size_t)r0 * FDIM + kofs + k8 * 8;
    const unsigned short* pB1 = wdt + wb + (size_t)(64 + r0) * FDIM + kofs + k8 * 8;

    unsigned short* dA0 = &lA[wave * 512];
    unsigned short* dA1 = &lA[2048 + wave * 512];
    unsigned short* dB0 = &lB[wave * 512];
    unsigned short* dB1 = &lB[2048 + wave * 512];

    const int wm = wave >> 1, wn = wave & 1;
    const int fr = lane & 15, kg = lane >> 4;

    floatx4 acc[4][4];
#pragma unroll
    for (int mi = 0; mi < 4; ++mi)
#pragma unroll
        for (int ni = 0; ni < 4; ++ni) {
            floatx4 z = {0.f, 0.f, 0.f, 0.f};
            acc[mi][ni] = z;
        }

    for (int ks = 0; ks < FDIM / 64; ++ks) {   // 64 steps of BK=32 over this K-half
        gl2lds16(pA0, dA0); gl2lds16(pA1, dA1);
        gl2lds16(pB0, dB0); gl2lds16(pB1, dB1);
        pA0 += 32; pA1 += 32; pB0 += 32; pB1 += 32;
        __syncthreads();
        short8 a[4], b[4];
#pragma unroll
        for (int mi = 0; mi < 4; ++mi)
            a[mi] = *(const short8*)&lA[(wm * 64 + mi * 16 + fr) * 32 + kg * 8];
#pragma unroll
        for (int ni = 0; ni < 4; ++ni)
            b[ni] = *(const short8*)&lB[(wn * 64 + ni * 16 + fr) * 32 + kg * 8];
#pragma unroll
        for (int mi = 0; mi < 4; ++mi)
#pragma unroll
            for (int ni = 0; ni < 4; ++ni)
                acc[mi][ni] = __builtin_amdgcn_mfma_f32_16x16x32_bf16(a[mi], b[ni], acc[mi][ni], 0, 0, 0);
        __syncthreads();
    }

    float* ob = obuf + (size_t)khalf * OBR * HDIM;
#pragma unroll
    for (int mi = 0; mi < 4; ++mi)
#pragma unroll
        for (int ni = 0; ni < 4; ++ni) {
            int c = htile * 128 + wn * 64 + ni * 16 + fr;
#pragma unroll
            for (int r = 0; r < 4; ++r) {
                int rr = wm * 64 + mi * 16 + kg * 4 + r;
                if (rowtile * 128 + rr < M)
                    ob[(size_t)(row0 + rr) * HDIM + c] = acc[mi][ni][r] * swt[rr];
            }
        }
}

// ---------------- combine: out[tok] = sum over 2 slots x 2 k-halves ----------------
__global__ void k_combine(const float* __restrict__ obuf, const int* __restrict__ tslot,
                          const int* __restrict__ offs, float* __restrict__ out) {
    int gid = blockIdx.x * 256 + threadIdx.x;
    int tok = gid >> 8;           // 256 threads per token
    int c = (gid & 255) * 4;
    int s0 = tslot[tok * 2], s1 = tslot[tok * 2 + 1];
    size_t r0 = (size_t)(offs[s0 >> 16] + (s0 & 0xFFFF));
    size_t r1 = (size_t)(offs[s1 >> 16] + (s1 & 0xFFFF));
    float4v v00 = *(const float4v*)(obuf + r0 * HDIM + c);
    float4v v01 = *(const float4v*)(obuf + ((size_t)OBR + r0) * HDIM + c);
    float4v v10 = *(const float4v*)(obuf + r1 * HDIM + c);
    float4v v11 = *(const float4v*)(obuf + ((size_t)OBR + r1) * HDIM + c);
    float4v s = v00 + v01 + v10 + v11;
    *(float4v*)(out + (size_t)tok * HDIM + c) = s;
}

extern "C" void kernel_launch(void* const* d_in, const int* in_sizes, int n_in,
                              void* d_out, int out_size, void* d_ws, size_t ws_size,
                              hipStream_t stream) {
    const float* x     = (const float*)d_in[0];  // [4096][1024]
    const float* wgate = (const float*)d_in[1];  // [1024][8]
    const float* wg    = (const float*)d_in[2];  // [8][1024][4096]
    const float* wu    = (const float*)d_in[3];  // [8][1024][4096]
    const float* wd    = (const float*)d_in[4];  // [8][4096][1024]
    float* out = (float*)d_out;

    char* ws = (char*)d_ws;
    size_t off = 0;
    unsigned short* xb  = (unsigned short*)(ws + off); off += (size_t)T_TOK * HDIM * 2;
    unsigned short* wgt = (unsigned short*)(ws + off); off += (size_t)NEXP * FDIM * HDIM * 2;
    unsigned short* wut = (unsigned short*)(ws + off); off += (size_t)NEXP * FDIM * HDIM * 2;
    unsigned short* wdt = (unsigned short*)(ws + off); off += (size_t)NEXP * HDIM * FDIM * 2;
    unsigned short* hbuf= (unsigned short*)(ws + off); off += (size_t)OBR * FDIM * 2;
    int*   ltok   = (int*)(ws + off);   off += (size_t)NEXP * CAP * 4;
    float* lwt    = (float*)(ws + off); off += (size_t)NEXP * CAP * 4;
    int*   tslot  = (int*)(ws + off);   off += (size_t)T_TOK * 2 * 4;
    int*   counts = (int*)(ws + off);   off += 256;
    int*   offs   = (int*)(ws + off);   off += 256;
    int*   wl     = (int*)(ws + off);   off += MAXWL * 4;
    int*   nwl    = (int*)(ws + off);   off += 256;
    int*   wl1    = (int*)(ws + off);   off += 64 * 4;
    int*   nwl1   = (int*)(ws + off);   off += 256;
    // obuf aliases wgt+wut (dead after gemm1): 2*OBR*HDIM*4 = 68 MB < 134 MB
    float* obuf = (float*)wgt;

    hipMemsetAsync(counts, 0, 32, stream);

    k_router<<<T_TOK / 4, 256, 0, stream>>>(x, wgate, xb, counts, ltok, lwt, tslot);
    k_transpose_cast<<<dim3(FDIM / 64, HDIM / 64, NEXP), 256, 0, stream>>>(wg, wgt, HDIM, FDIM);
    k_transpose_cast<<<dim3(FDIM / 64, HDIM / 64, NEXP), 256, 0, stream>>>(wu, wut, HDIM, FDIM);
    k_transpose_cast<<<dim3(HDIM / 64, FDIM / 64, NEXP), 256, 0, stream>>>(wd, wdt, FDIM, HDIM);
    k_prefix<<<1, 64, 0, stream>>>(counts, offs, wl, nwl, wl1, nwl1);
    k_gemm1<<<dim3(FDIM / 64, NT1MAX), 512, 0, stream>>>(xb, wgt, wut, counts, offs, ltok, wl1, nwl1, hbuf);
    k_gemm2<<<dim3(HDIM / 128, 72, 2), 256, 0, stream>>>(hbuf, wdt, counts, offs, lwt, wl, nwl, obuf);
    k_combine<<<T_TOK * HDIM / 1024, 256, 0, stream>>>(obuf, tslot, offs, out);
}

// Round 3
// 834.207 us; speedup vs baseline: 1.0891x; 1.0891x over previous
//
#include <hip/hip_runtime.h>
#include <hip/hip_bf16.h>

#define T_TOK 4096
#define HDIM  1024
#define FDIM  4096
#define NEXP  8
#define CAP   4096
#define MAXWL 128
#define OBR   (2 * T_TOK + 128)   // compact rows incl. padding

typedef __attribute__((ext_vector_type(8))) short short8;
typedef __attribute__((ext_vector_type(4))) float floatx4;
typedef __attribute__((ext_vector_type(4))) float float4v;
typedef __attribute__((ext_vector_type(4))) unsigned short ushort4v;

__device__ __forceinline__ unsigned short f2bf(float f) {
    union { float f; unsigned int u; } v; v.f = f;
    unsigned int u = v.u;
    u += 0x7fffu + ((u >> 16) & 1u);   // round-to-nearest-even
    return (unsigned short)(u >> 16);
}

__device__ __forceinline__ void gl2lds16(const void* g, void* l) {
    __builtin_amdgcn_global_load_lds(
        (const __attribute__((address_space(1))) unsigned int*)g,
        (__attribute__((address_space(3))) unsigned int*)l,
        16, 0, 0);
}

// ---------------- transpose + cast: src [R][C] fp32 -> dst [C][R] bf16, 64x64 tiles ----------------
__global__ void k_transpose_cast(const float* __restrict__ src, unsigned short* __restrict__ dst,
                                 int R, int C) {
    __shared__ float tile[64][65];
    size_t base = (size_t)blockIdx.z * (size_t)R * (size_t)C;
    int c0 = blockIdx.x * 64, r0 = blockIdx.y * 64;
    int lx = threadIdx.x & 15, ly = threadIdx.x >> 4;  // lx: float4 col, ly: 0..15
#pragma unroll
    for (int i = 0; i < 4; ++i) {
        int rr = i * 16 + ly;
        float4v v = *(const float4v*)(src + base + (size_t)(r0 + rr) * C + c0 + lx * 4);
        tile[rr][lx * 4 + 0] = v[0]; tile[rr][lx * 4 + 1] = v[1];
        tile[rr][lx * 4 + 2] = v[2]; tile[rr][lx * 4 + 3] = v[3];
    }
    __syncthreads();
#pragma unroll
    for (int i = 0; i < 4; ++i) {
        int cc = i * 16 + ly;
        ushort4v o = { f2bf(tile[lx * 4 + 0][cc]), f2bf(tile[lx * 4 + 1][cc]),
                       f2bf(tile[lx * 4 + 2][cc]), f2bf(tile[lx * 4 + 3][cc]) };
        *(ushort4v*)(dst + base + (size_t)(c0 + cc) * R + r0 + lx * 4) = o;
    }
}

// ---------------- router (+ x cast): logits, softmax, top-2, lists, per-token slots ----------------
__global__ void k_router(const float* __restrict__ x, const float* __restrict__ wgate,
                         unsigned short* __restrict__ xb,
                         int* __restrict__ counts, int* __restrict__ ltok,
                         float* __restrict__ lwt, int* __restrict__ tslot) {
    int lane = threadIdx.x & 63;
    int tok = blockIdx.x * 4 + (threadIdx.x >> 6);
    const float* xr = x + (size_t)tok * HDIM;
    unsigned short* xbr = xb + (size_t)tok * HDIM;
    float acc[NEXP];
#pragma unroll
    for (int e = 0; e < NEXP; ++e) acc[e] = 0.f;
    for (int it = 0; it < HDIM / 256; ++it) {
        int h0 = it * 256 + lane * 4;
        float4v xv = *(const float4v*)(xr + h0);
        ushort4v xo = { f2bf(xv[0]), f2bf(xv[1]), f2bf(xv[2]), f2bf(xv[3]) };
        *(ushort4v*)(xbr + h0) = xo;
#pragma unroll
        for (int j = 0; j < 4; ++j) {
            float4v w0 = *(const float4v*)(wgate + (size_t)(h0 + j) * NEXP);
            float4v w1 = *(const float4v*)(wgate + (size_t)(h0 + j) * NEXP + 4);
            float xs = xv[j];
            acc[0] += xs * w0[0]; acc[1] += xs * w0[1];
            acc[2] += xs * w0[2]; acc[3] += xs * w0[3];
            acc[4] += xs * w1[0]; acc[5] += xs * w1[1];
            acc[6] += xs * w1[2]; acc[7] += xs * w1[3];
        }
    }
#pragma unroll
    for (int off = 32; off >= 1; off >>= 1)
#pragma unroll
        for (int e = 0; e < NEXP; ++e)
            acc[e] += __shfl_xor(acc[e], off, 64);
    if (lane == 0) {
        float m = acc[0];
#pragma unroll
        for (int e = 1; e < NEXP; ++e) m = fmaxf(m, acc[e]);
        float p[NEXP], s = 0.f;
#pragma unroll
        for (int e = 0; e < NEXP; ++e) { p[e] = __expf(acc[e] - m); s += p[e]; }
        float inv = 1.f / s;
#pragma unroll
        for (int e = 0; e < NEXP; ++e) p[e] *= inv;
        int e0 = 0; float b0 = p[0];
#pragma unroll
        for (int e = 1; e < NEXP; ++e) if (p[e] > b0) { b0 = p[e]; e0 = e; }
        int e1 = -1; float b1 = -1.f;
#pragma unroll
        for (int e = 0; e < NEXP; ++e) if (e != e0 && p[e] > b1) { b1 = p[e]; e1 = e; }
        int p0 = atomicAdd(&counts[e0], 1);
        ltok[e0 * CAP + p0] = tok; lwt[e0 * CAP + p0] = b0;
        int p1 = atomicAdd(&counts[e1], 1);
        ltok[e1 * CAP + p1] = tok; lwt[e1 * CAP + p1] = b1;
        tslot[tok * 2]     = (e0 << 16) | p0;
        tslot[tok * 2 + 1] = (e1 << 16) | p1;
    }
}

// prefix sums + compact (expert, rowtile) worklist. Sum of counts == 8192 so nwl <= 71.
__global__ void k_prefix(const int* __restrict__ counts, int* __restrict__ offs,
                         int* __restrict__ wl, int* __restrict__ nwl) {
    if (threadIdx.x == 0) {
        int s = 0;
#pragma unroll
        for (int e = 0; e < NEXP; ++e) { offs[e] = s; s += counts[e]; }
        int n = 0;
        for (int e = 0; e < NEXP; ++e)
            for (int r = 0; r * 128 < counts[e] && n < MAXWL; ++r)
                wl[n++] = (e << 8) | r;
        nwl[0] = n;
    }
}

// ---------------- GEMM1 v4: h = silu(x@Wg) * (x@Wu), 128 rows x 64 cols per matrix ----------------
// Round-0 structure + (a) T2 XOR swizzle (chunk ^= (row>>1)&3, both sides: pre-swizzled
// gl2lds SOURCE + swizzled ds_read) -> 8-way quarter-wave bank conflict eliminated;
// (b) minimum-2-phase reorder: double-buffered LDS, stage NEXT tile before compute of
// CURRENT, one __syncthreads per K-step (stage latency hides under ds_read+MFMA).
// Occupancy preserved: LDS 33.4 KB -> 4 blocks/CU, 256 threads.
__global__ __launch_bounds__(256, 4)
void k_gemm1(const unsigned short* __restrict__ xb,    // [T][H] bf16
             const unsigned short* __restrict__ wgt,   // [E][F][H] bf16
             const unsigned short* __restrict__ wut,   // [E][F][H]
             const int* __restrict__ counts, const int* __restrict__ offs,
             const int* __restrict__ ltok,
             const int* __restrict__ wl, const int* __restrict__ nwl,
             unsigned short* __restrict__ hbuf)        // [OBR][F] bf16
{
    if ((int)blockIdx.y >= nwl[0]) return;
    const int w = wl[blockIdx.y];
    const int e = w >> 8, rowtile = w & 255;
    const int M = counts[e];
    const int ftile = blockIdx.x;  // 0..63 (64 f-cols per block)

    __shared__ __align__(16) unsigned short lA[2][128 * 32];   // 2 x 8 KB
    __shared__ __align__(16) unsigned short lBg[2][64 * 32];   // 2 x 4 KB
    __shared__ __align__(16) unsigned short lBu[2][64 * 32];   // 2 x 4 KB
    __shared__ int stok[128];

    const int t = threadIdx.x;
    const int wave = t >> 6, lane = t & 63;

    if (t < 128) {
        int i = rowtile * 128 + t;
        stok[t] = (i < M) ? ltok[e * CAP + i] : ltok[e * CAP];
    }
    __syncthreads();

    const int r0 = t >> 2, k8 = t & 3;
    const int sw0 = (k8 ^ ((r0 >> 1) & 3)) * 8;        // inverse-swizzled source chunk
    const unsigned short* pA0 = xb + (size_t)stok[r0] * HDIM + sw0;
    const unsigned short* pA1 = xb + (size_t)stok[r0 + 64] * HDIM + sw0;
    const size_t wbase = (size_t)e * FDIM * HDIM + (size_t)(ftile * 64) * HDIM;
    const unsigned short* pG0 = wgt + wbase + (size_t)r0 * HDIM + sw0;
    const unsigned short* pU0 = wut + wbase + (size_t)r0 * HDIM + sw0;

    const int wm = wave >> 1, wn = wave & 1;
    const int fr = lane & 15, kg = lane >> 4;
    const int cswz = (kg ^ ((fr >> 1) & 3)) * 8;       // swizzled read chunk

    floatx4 accg[4][2], accu[4][2];
#pragma unroll
    for (int mi = 0; mi < 4; ++mi)
#pragma unroll
        for (int ni = 0; ni < 2; ++ni) {
            floatx4 z = {0.f, 0.f, 0.f, 0.f};
            accg[mi][ni] = z; accu[mi][ni] = z;
        }

    auto stage = [&](int b) {   // 4 gl2lds per thread; dest linear (wave-uniform base)
        gl2lds16(pA0, &lA[b][wave * 512]);        pA0 += 32;
        gl2lds16(pA1, &lA[b][2048 + wave * 512]); pA1 += 32;
        gl2lds16(pG0, &lBg[b][wave * 512]);       pG0 += 32;
        gl2lds16(pU0, &lBu[b][wave * 512]);       pU0 += 32;
    };
    auto compute = [&](int b) {
        short8 a[4], g[2], u[2];
#pragma unroll
        for (int mi = 0; mi < 4; ++mi)
            a[mi] = *(const short8*)&lA[b][(wm * 64 + mi * 16 + fr) * 32 + cswz];
#pragma unroll
        for (int ni = 0; ni < 2; ++ni) {
            g[ni] = *(const short8*)&lBg[b][(wn * 32 + ni * 16 + fr) * 32 + cswz];
            u[ni] = *(const short8*)&lBu[b][(wn * 32 + ni * 16 + fr) * 32 + cswz];
        }
#pragma unroll
        for (int mi = 0; mi < 4; ++mi)
#pragma unroll
            for (int ni = 0; ni < 2; ++ni) {
                accg[mi][ni] = __builtin_amdgcn_mfma_f32_16x16x32_bf16(a[mi], g[ni], accg[mi][ni], 0, 0, 0);
                accu[mi][ni] = __builtin_amdgcn_mfma_f32_16x16x32_bf16(a[mi], u[ni], accu[mi][ni], 0, 0, 0);
            }
    };

    // 32 K-steps of BK=32, double-buffered, stage-ahead by 1
    stage(0);
    __syncthreads();
#pragma unroll 1
    for (int it = 0; it < 16; ++it) {
        stage(1);          // K-step 2it+1
        compute(0);        // K-step 2it
        __syncthreads();   // drains stage(1) loads; all reads of buf0 done
        if (it < 15) stage(0);   // K-step 2it+2
        compute(1);
        __syncthreads();
    }

    const int hrow0 = offs[e] + rowtile * 128;
#pragma unroll
    for (int mi = 0; mi < 4; ++mi)
#pragma unroll
        for (int ni = 0; ni < 2; ++ni) {
            int c = ftile * 64 + wn * 32 + ni * 16 + fr;
#pragma unroll
            for (int r = 0; r < 4; ++r) {
                int rr = wm * 64 + mi * 16 + kg * 4 + r;
                if (rowtile * 128 + rr < M) {
                    float g = accg[mi][ni][r];
                    float val = (g / (1.f + __expf(-g))) * accu[mi][ni][r];
                    hbuf[(size_t)(hrow0 + rr) * FDIM + c] = f2bf(val);
                }
            }
        }
}

// ---------------- GEMM2 v4: obuf[khalf][row] = w * (h @ Wd^T), split-K=2 ----------------
// Same two changes as gemm1: T2 swizzle + double-buffered stage-ahead.
__global__ __launch_bounds__(256, 2)
void k_gemm2(const unsigned short* __restrict__ hbuf,  // [OBR][F] bf16
             const unsigned short* __restrict__ wdt,   // [E][H][F] bf16
             const int* __restrict__ counts, const int* __restrict__ offs,
             const float* __restrict__ lwt,
             const int* __restrict__ wl, const int* __restrict__ nwl,
             float* __restrict__ obuf)                 // [2][OBR][H] fp32
{
    if ((int)blockIdx.y >= nwl[0]) return;
    const int w = wl[blockIdx.y];
    const int e = w >> 8, rowtile = w & 255;
    const int M = counts[e];
    const int htile = blockIdx.x;  // 0..7
    const int khalf = blockIdx.z;  // 0..1

    __shared__ __align__(16) unsigned short lA[2][128 * 32];
    __shared__ __align__(16) unsigned short lB[2][128 * 32];
    __shared__ float swt[128];

    const int t = threadIdx.x;
    const int wave = t >> 6, lane = t & 63;

    if (t < 128) {
        int i = rowtile * 128 + t;
        swt[t] = (i < M) ? lwt[e * CAP + i] : 0.f;
    }

    const int row0 = offs[e] + rowtile * 128;
    const int r0 = t >> 2, k8 = t & 3;
    const int kofs = khalf * (FDIM / 2);
    const int sw0 = (k8 ^ ((r0 >> 1) & 3)) * 8;        // inverse-swizzled source chunk
    const unsigned short* pA0 = hbuf + (size_t)(row0 + r0) * FDIM + kofs + sw0;
    const unsigned short* pA1 = hbuf + (size_t)(row0 + 64 + r0) * FDIM + kofs + sw0;
    const size_t wb = (size_t)e * HDIM * FDIM + (size_t)(htile * 128) * FDIM;
    const unsigned short* pB0 = wdt + wb + (size_t)r0 * FDIM + kofs + sw0;
    const unsigned short* pB1 = wdt + wb + (size_t)(64 + r0) * FDIM + kofs + sw0;

    const int wm = wave >> 1, wn = wave & 1;
    const int fr = lane & 15, kg = lane >> 4;
    const int cswz = (kg ^ ((fr >> 1) & 3)) * 8;       // swizzled read chunk

    floatx4 acc[4][4];
#pragma unroll
    for (int mi = 0; mi < 4; ++mi)
#pragma unroll
        for (int ni = 0; ni < 4; ++ni) {
            floatx4 z = {0.f, 0.f, 0.f, 0.f};
            acc[mi][ni] = z;
        }

    auto stage = [&](int b) {
        gl2lds16(pA0, &lA[b][wave * 512]);        pA0 += 32;
        gl2lds16(pA1, &lA[b][2048 + wave * 512]); pA1 += 32;
        gl2lds16(pB0, &lB[b][wave * 512]);        pB0 += 32;
        gl2lds16(pB1, &lB[b][2048 + wave * 512]); pB1 += 32;
    };
    auto compute = [&](int b) {
        short8 a[4], bb[4];
#pragma unroll
        for (int mi = 0; mi < 4; ++mi)
            a[mi] = *(const short8*)&lA[b][(wm * 64 + mi * 16 + fr) * 32 + cswz];
#pragma unroll
        for (int ni = 0; ni < 4; ++ni)
            bb[ni] = *(const short8*)&lB[b][(wn * 64 + ni * 16 + fr) * 32 + cswz];
#pragma unroll
        for (int mi = 0; mi < 4; ++mi)
#pragma unroll
            for (int ni = 0; ni < 4; ++ni)
                acc[mi][ni] = __builtin_amdgcn_mfma_f32_16x16x32_bf16(a[mi], bb[ni], acc[mi][ni], 0, 0, 0);
    };

    // 64 K-steps of BK=32 over this K-half, double-buffered, stage-ahead by 1
    stage(0);
    __syncthreads();
#pragma unroll 1
    for (int it = 0; it < 32; ++it) {
        stage(1);
        compute(0);
        __syncthreads();
        if (it < 31) stage(0);
        compute(1);
        __syncthreads();
    }

    float* ob = obuf + (size_t)khalf * OBR * HDIM;
#pragma unroll
    for (int mi = 0; mi < 4; ++mi)
#pragma unroll
        for (int ni = 0; ni < 4; ++ni) {
            int c = htile * 128 + wn * 64 + ni * 16 + fr;
#pragma unroll
            for (int r = 0; r < 4; ++r) {
                int rr = wm * 64 + mi * 16 + kg * 4 + r;
                if (rowtile * 128 + rr < M)
                    ob[(size_t)(row0 + rr) * HDIM + c] = acc[mi][ni][r] * swt[rr];
            }
        }
}

// ---------------- combine: out[tok] = sum over 2 slots x 2 k-halves ----------------
__global__ void k_combine(const float* __restrict__ obuf, const int* __restrict__ tslot,
                          const int* __restrict__ offs, float* __restrict__ out) {
    int gid = blockIdx.x * 256 + threadIdx.x;
    int tok = gid >> 8;           // 256 threads per token
    int c = (gid & 255) * 4;
    int s0 = tslot[tok * 2], s1 = tslot[tok * 2 + 1];
    size_t r0 = (size_t)(offs[s0 >> 16] + (s0 & 0xFFFF));
    size_t r1 = (size_t)(offs[s1 >> 16] + (s1 & 0xFFFF));
    float4v v00 = *(const float4v*)(obuf + r0 * HDIM + c);
    float4v v01 = *(const float4v*)(obuf + ((size_t)OBR + r0) * HDIM + c);
    float4v v10 = *(const float4v*)(obuf + r1 * HDIM + c);
    float4v v11 = *(const float4v*)(obuf + ((size_t)OBR + r1) * HDIM + c);
    float4v s = v00 + v01 + v10 + v11;
    *(float4v*)(out + (size_t)tok * HDIM + c) = s;
}

extern "C" void kernel_launch(void* const* d_in, const int* in_sizes, int n_in,
                              void* d_out, int out_size, void* d_ws, size_t ws_size,
                              hipStream_t stream) {
    const float* x     = (const float*)d_in[0];  // [4096][1024]
    const float* wgate = (const float*)d_in[1];  // [1024][8]
    const float* wg    = (const float*)d_in[2];  // [8][1024][4096]
    const float* wu    = (const float*)d_in[3];  // [8][1024][4096]
    const float* wd    = (const float*)d_in[4];  // [8][4096][1024]
    float* out = (float*)d_out;

    char* ws = (char*)d_ws;
    size_t off = 0;
    unsigned short* xb  = (unsigned short*)(ws + off); off += (size_t)T_TOK * HDIM * 2;
    unsigned short* wgt = (unsigned short*)(ws + off); off += (size_t)NEXP * FDIM * HDIM * 2;
    unsigned short* wut = (unsigned short*)(ws + off); off += (size_t)NEXP * FDIM * HDIM * 2;
    unsigned short* wdt = (unsigned short*)(ws + off); off += (size_t)NEXP * HDIM * FDIM * 2;
    unsigned short* hbuf= (unsigned short*)(ws + off); off += (size_t)OBR * FDIM * 2;
    int*   ltok   = (int*)(ws + off);   off += (size_t)NEXP * CAP * 4;
    float* lwt    = (float*)(ws + off); off += (size_t)NEXP * CAP * 4;
    int*   tslot  = (int*)(ws + off);   off += (size_t)T_TOK * 2 * 4;
    int*   counts = (int*)(ws + off);   off += 256;
    int*   offs   = (int*)(ws + off);   off += 256;
    int*   wl     = (int*)(ws + off);   off += MAXWL * 4;
    int*   nwl    = (int*)(ws + off);   off += 256;
    // obuf aliases wgt+wut (dead after gemm1): 2*OBR*HDIM*4 = 68 MB < 134 MB
    float* obuf = (float*)wgt;

    hipMemsetAsync(counts, 0, 32, stream);

    k_router<<<T_TOK / 4, 256, 0, stream>>>(x, wgate, xb, counts, ltok, lwt, tslot);
    k_transpose_cast<<<dim3(FDIM / 64, HDIM / 64, NEXP), 256, 0, stream>>>(wg, wgt, HDIM, FDIM);
    k_transpose_cast<<<dim3(FDIM / 64, HDIM / 64, NEXP), 256, 0, stream>>>(wu, wut, HDIM, FDIM);
    k_transpose_cast<<<dim3(HDIM / 64, FDIM / 64, NEXP), 256, 0, stream>>>(wd, wdt, FDIM, HDIM);
    k_prefix<<<1, 64, 0, stream>>>(counts, offs, wl, nwl);
    k_gemm1<<<dim3(FDIM / 64, 72), 256, 0, stream>>>(xb, wgt, wut, counts, offs, ltok, wl, nwl, hbuf);
    k_gemm2<<<dim3(HDIM / 128, 72, 2), 256, 0, stream>>>(hbuf, wdt, counts, offs, lwt, wl, nwl, obuf);
    k_combine<<<T_TOK * HDIM / 1024, 256, 0, stream>>>(obuf, tslot, offs, out);
}

// Round 4
// 827.522 us; speedup vs baseline: 1.0979x; 1.0081x over previous
//
#include <hip/hip_runtime.h>
#include <hip/hip_bf16.h>

#define T_TOK 4096
#define HDIM  1024
#define FDIM  4096
#define NEXP  8
#define CAP   4096
#define MAXWL 128
#define OBR   (2 * T_TOK + 128)   // compact rows incl. padding

typedef __attribute__((ext_vector_type(8))) short short8;
typedef __attribute__((ext_vector_type(4))) float floatx4;
typedef __attribute__((ext_vector_type(4))) float float4v;
typedef __attribute__((ext_vector_type(4))) unsigned short ushort4v;

__device__ __forceinline__ unsigned short f2bf(float f) {
    union { float f; unsigned int u; } v; v.f = f;
    unsigned int u = v.u;
    u += 0x7fffu + ((u >> 16) & 1u);   // round-to-nearest-even
    return (unsigned short)(u >> 16);
}

__device__ __forceinline__ void gl2lds16(const void* g, void* l) {
    __builtin_amdgcn_global_load_lds(
        (const __attribute__((address_space(1))) unsigned int*)g,
        (__attribute__((address_space(3))) unsigned int*)l,
        16, 0, 0);
}

// ---------------- transpose + cast: src [R][C] fp32 -> dst [C][R] bf16, 64x64 tiles ----------------
__global__ void k_transpose_cast(const float* __restrict__ src, unsigned short* __restrict__ dst,
                                 int R, int C) {
    __shared__ float tile[64][65];
    size_t base = (size_t)blockIdx.z * (size_t)R * (size_t)C;
    int c0 = blockIdx.x * 64, r0 = blockIdx.y * 64;
    int lx = threadIdx.x & 15, ly = threadIdx.x >> 4;  // lx: float4 col, ly: 0..15
#pragma unroll
    for (int i = 0; i < 4; ++i) {
        int rr = i * 16 + ly;
        float4v v = *(const float4v*)(src + base + (size_t)(r0 + rr) * C + c0 + lx * 4);
        tile[rr][lx * 4 + 0] = v[0]; tile[rr][lx * 4 + 1] = v[1];
        tile[rr][lx * 4 + 2] = v[2]; tile[rr][lx * 4 + 3] = v[3];
    }
    __syncthreads();
#pragma unroll
    for (int i = 0; i < 4; ++i) {
        int cc = i * 16 + ly;
        ushort4v o = { f2bf(tile[lx * 4 + 0][cc]), f2bf(tile[lx * 4 + 1][cc]),
                       f2bf(tile[lx * 4 + 2][cc]), f2bf(tile[lx * 4 + 3][cc]) };
        *(ushort4v*)(dst + base + (size_t)(c0 + cc) * R + r0 + lx * 4) = o;
    }
}

// merged wg+wu transpose (same shape): blockIdx.z = matrix*8 + expert
__global__ void k_transpose_cast2(const float* __restrict__ s0, const float* __restrict__ s1,
                                  unsigned short* __restrict__ d0, unsigned short* __restrict__ d1) {
    const int R = HDIM, C = FDIM;
    __shared__ float tile[64][65];
    int m = blockIdx.z >> 3, zz = blockIdx.z & 7;
    const float* src = (m ? s1 : s0);
    unsigned short* dst = (m ? d1 : d0);
    size_t base = (size_t)zz * (size_t)R * (size_t)C;
    int c0 = blockIdx.x * 64, r0 = blockIdx.y * 64;
    int lx = threadIdx.x & 15, ly = threadIdx.x >> 4;
#pragma unroll
    for (int i = 0; i < 4; ++i) {
        int rr = i * 16 + ly;
        float4v v = *(const float4v*)(src + base + (size_t)(r0 + rr) * C + c0 + lx * 4);
        tile[rr][lx * 4 + 0] = v[0]; tile[rr][lx * 4 + 1] = v[1];
        tile[rr][lx * 4 + 2] = v[2]; tile[rr][lx * 4 + 3] = v[3];
    }
    __syncthreads();
#pragma unroll
    for (int i = 0; i < 4; ++i) {
        int cc = i * 16 + ly;
        ushort4v o = { f2bf(tile[lx * 4 + 0][cc]), f2bf(tile[lx * 4 + 1][cc]),
                       f2bf(tile[lx * 4 + 2][cc]), f2bf(tile[lx * 4 + 3][cc]) };
        *(ushort4v*)(dst + base + (size_t)(c0 + cc) * R + r0 + lx * 4) = o;
    }
}

// ---------------- router (+ x cast): logits, softmax, top-2, lists, per-token slots ----------------
__global__ void k_router(const float* __restrict__ x, const float* __restrict__ wgate,
                         unsigned short* __restrict__ xb,
                         int* __restrict__ counts, int* __restrict__ ltok,
                         float* __restrict__ lwt, int* __restrict__ tslot) {
    int lane = threadIdx.x & 63;
    int tok = blockIdx.x * 4 + (threadIdx.x >> 6);
    const float* xr = x + (size_t)tok * HDIM;
    unsigned short* xbr = xb + (size_t)tok * HDIM;
    float acc[NEXP];
#pragma unroll
    for (int e = 0; e < NEXP; ++e) acc[e] = 0.f;
    for (int it = 0; it < HDIM / 256; ++it) {
        int h0 = it * 256 + lane * 4;
        float4v xv = *(const float4v*)(xr + h0);
        ushort4v xo = { f2bf(xv[0]), f2bf(xv[1]), f2bf(xv[2]), f2bf(xv[3]) };
        *(ushort4v*)(xbr + h0) = xo;
#pragma unroll
        for (int j = 0; j < 4; ++j) {
            float4v w0 = *(const float4v*)(wgate + (size_t)(h0 + j) * NEXP);
            float4v w1 = *(const float4v*)(wgate + (size_t)(h0 + j) * NEXP + 4);
            float xs = xv[j];
            acc[0] += xs * w0[0]; acc[1] += xs * w0[1];
            acc[2] += xs * w0[2]; acc[3] += xs * w0[3];
            acc[4] += xs * w1[0]; acc[5] += xs * w1[1];
            acc[6] += xs * w1[2]; acc[7] += xs * w1[3];
        }
    }
#pragma unroll
    for (int off = 32; off >= 1; off >>= 1)
#pragma unroll
        for (int e = 0; e < NEXP; ++e)
            acc[e] += __shfl_xor(acc[e], off, 64);
    if (lane == 0) {
        float m = acc[0];
#pragma unroll
        for (int e = 1; e < NEXP; ++e) m = fmaxf(m, acc[e]);
        float p[NEXP], s = 0.f;
#pragma unroll
        for (int e = 0; e < NEXP; ++e) { p[e] = __expf(acc[e] - m); s += p[e]; }
        float inv = 1.f / s;
#pragma unroll
        for (int e = 0; e < NEXP; ++e) p[e] *= inv;
        int e0 = 0; float b0 = p[0];
#pragma unroll
        for (int e = 1; e < NEXP; ++e) if (p[e] > b0) { b0 = p[e]; e0 = e; }
        int e1 = -1; float b1 = -1.f;
#pragma unroll
        for (int e = 0; e < NEXP; ++e) if (e != e0 && p[e] > b1) { b1 = p[e]; e1 = e; }
        int p0 = atomicAdd(&counts[e0], 1);
        ltok[e0 * CAP + p0] = tok; lwt[e0 * CAP + p0] = b0;
        int p1 = atomicAdd(&counts[e1], 1);
        ltok[e1 * CAP + p1] = tok; lwt[e1 * CAP + p1] = b1;
        tslot[tok * 2]     = (e0 << 16) | p0;
        tslot[tok * 2 + 1] = (e1 << 16) | p1;
    }
}

// prefix sums + compact (expert, rowtile) worklist. Sum of counts == 8192 so nwl <= 71.
__global__ void k_prefix(const int* __restrict__ counts, int* __restrict__ offs,
                         int* __restrict__ wl, int* __restrict__ nwl) {
    if (threadIdx.x == 0) {
        int s = 0;
#pragma unroll
        for (int e = 0; e < NEXP; ++e) { offs[e] = s; s += counts[e]; }
        int n = 0;
        for (int e = 0; e < NEXP; ++e)
            for (int r = 0; r * 128 < counts[e] && n < MAXWL; ++r)
                wl[n++] = (e << 8) | r;
        nwl[0] = n;
    }
}

// ---------------- GEMM1 v5: h = silu(x@Wg) * (x@Wu), 128 rows x 64 cols per matrix ----------------
// v4 structure (T2 swizzle both-sides + double-buffered stage-ahead) + XCD-pinned
// block decode: 1D grid, ftile === bid (mod 8) -> each (e,ftile) weight panel is
// re-read ~8.5x from ONE XCD's L2 instead of L3; A-panel-sharing blocks (same
// rowtile) occupy 64 consecutive ids -> temporally co-dispatched.
__global__ __launch_bounds__(256, 4)
void k_gemm1(const unsigned short* __restrict__ xb,    // [T][H] bf16
             const unsigned short* __restrict__ wgt,   // [E][F][H] bf16
             const unsigned short* __restrict__ wut,   // [E][F][H]
             const int* __restrict__ counts, const int* __restrict__ offs,
             const int* __restrict__ ltok,
             const int* __restrict__ wl, const int* __restrict__ nwl,
             unsigned short* __restrict__ hbuf)        // [OBR][F] bf16
{
    // decode: bid = xcd + 8*fhi + 64*by ; ftile = xcd + 8*fhi (so ftile % 8 == bid % 8)
    const int bid = blockIdx.x;
    const int xcd = bid & 7;
    const int jj  = bid >> 3;
    const int fhi = jj & 7;
    const int by  = jj >> 3;         // 0..71
    if (by >= nwl[0]) return;
    const int ftile = xcd + 8 * fhi; // 0..63
    const int w = wl[by];
    const int e = w >> 8, rowtile = w & 255;
    const int M = counts[e];

    __shared__ __align__(16) unsigned short lA[2][128 * 32];   // 2 x 8 KB
    __shared__ __align__(16) unsigned short lBg[2][64 * 32];   // 2 x 4 KB
    __shared__ __align__(16) unsigned short lBu[2][64 * 32];   // 2 x 4 KB
    __shared__ int stok[128];

    const int t = threadIdx.x;
    const int wave = t >> 6, lane = t & 63;

    if (t < 128) {
        int i = rowtile * 128 + t;
        stok[t] = (i < M) ? ltok[e * CAP + i] : ltok[e * CAP];
    }
    __syncthreads();

    const int r0 = t >> 2, k8 = t & 3;
    const int sw0 = (k8 ^ ((r0 >> 1) & 3)) * 8;        // inverse-swizzled source chunk
    const unsigned short* pA0 = xb + (size_t)stok[r0] * HDIM + sw0;
    const unsigned short* pA1 = xb + (size_t)stok[r0 + 64] * HDIM + sw0;
    const size_t wbase = (size_t)e * FDIM * HDIM + (size_t)(ftile * 64) * HDIM;
    const unsigned short* pG0 = wgt + wbase + (size_t)r0 * HDIM + sw0;
    const unsigned short* pU0 = wut + wbase + (size_t)r0 * HDIM + sw0;

    const int wm = wave >> 1, wn = wave & 1;
    const int fr = lane & 15, kg = lane >> 4;
    const int cswz = (kg ^ ((fr >> 1) & 3)) * 8;       // swizzled read chunk

    floatx4 accg[4][2], accu[4][2];
#pragma unroll
    for (int mi = 0; mi < 4; ++mi)
#pragma unroll
        for (int ni = 0; ni < 2; ++ni) {
            floatx4 z = {0.f, 0.f, 0.f, 0.f};
            accg[mi][ni] = z; accu[mi][ni] = z;
        }

    auto stage = [&](int b) {   // 4 gl2lds per thread; dest linear (wave-uniform base)
        gl2lds16(pA0, &lA[b][wave * 512]);        pA0 += 32;
        gl2lds16(pA1, &lA[b][2048 + wave * 512]); pA1 += 32;
        gl2lds16(pG0, &lBg[b][wave * 512]);       pG0 += 32;
        gl2lds16(pU0, &lBu[b][wave * 512]);       pU0 += 32;
    };
    auto compute = [&](int b) {
        short8 a[4], g[2], u[2];
#pragma unroll
        for (int mi = 0; mi < 4; ++mi)
            a[mi] = *(const short8*)&lA[b][(wm * 64 + mi * 16 + fr) * 32 + cswz];
#pragma unroll
        for (int ni = 0; ni < 2; ++ni) {
            g[ni] = *(const short8*)&lBg[b][(wn * 32 + ni * 16 + fr) * 32 + cswz];
            u[ni] = *(const short8*)&lBu[b][(wn * 32 + ni * 16 + fr) * 32 + cswz];
        }
#pragma unroll
        for (int mi = 0; mi < 4; ++mi)
#pragma unroll
            for (int ni = 0; ni < 2; ++ni) {
                accg[mi][ni] = __builtin_amdgcn_mfma_f32_16x16x32_bf16(a[mi], g[ni], accg[mi][ni], 0, 0, 0);
                accu[mi][ni] = __builtin_amdgcn_mfma_f32_16x16x32_bf16(a[mi], u[ni], accu[mi][ni], 0, 0, 0);
            }
    };

    // 32 K-steps of BK=32, double-buffered, stage-ahead by 1
    stage(0);
    __syncthreads();
#pragma unroll 1
    for (int it = 0; it < 16; ++it) {
        stage(1);          // K-step 2it+1
        compute(0);        // K-step 2it
        __syncthreads();   // drains stage(1) loads; all reads of buf0 done
        if (it < 15) stage(0);   // K-step 2it+2
        compute(1);
        __syncthreads();
    }

    const int hrow0 = offs[e] + rowtile * 128;
#pragma unroll
    for (int mi = 0; mi < 4; ++mi)
#pragma unroll
        for (int ni = 0; ni < 2; ++ni) {
            int c = ftile * 64 + wn * 32 + ni * 16 + fr;
#pragma unroll
            for (int r = 0; r < 4; ++r) {
                int rr = wm * 64 + mi * 16 + kg * 4 + r;
                if (rowtile * 128 + rr < M) {
                    float g = accg[mi][ni][r];
                    float val = (g / (1.f + __expf(-g))) * accu[mi][ni][r];
                    hbuf[(size_t)(hrow0 + rr) * FDIM + c] = f2bf(val);
                }
            }
        }
}

// ---------------- GEMM2 v5: obuf[khalf][row] = w * (h @ Wd^T), split-K=2 ----------------
// Same v4 structure + XCD-pinned decode: htile === bid (mod 8) -> wdt panels re-read
// from one XCD's L2 across rowtiles; A-sharing blocks (16 per rowtile) consecutive.
__global__ __launch_bounds__(256, 4)
void k_gemm2(const unsigned short* __restrict__ hbuf,  // [OBR][F] bf16
             const unsigned short* __restrict__ wdt,   // [E][H][F] bf16
             const int* __restrict__ counts, const int* __restrict__ offs,
             const float* __restrict__ lwt,
             const int* __restrict__ wl, const int* __restrict__ nwl,
             float* __restrict__ obuf)                 // [2][OBR][H] fp32
{
    // decode: bid = htile + 8*(khalf + 2*by)
    const int bid = blockIdx.x;
    const int htile = bid & 7;
    const int jj = bid >> 3;
    const int khalf = jj & 1;
    const int by = jj >> 1;          // 0..71
    if (by >= nwl[0]) return;
    const int w = wl[by];
    const int e = w >> 8, rowtile = w & 255;
    const int M = counts[e];

    __shared__ __align__(16) unsigned short lA[2][128 * 32];
    __shared__ __align__(16) unsigned short lB[2][128 * 32];
    __shared__ float swt[128];

    const int t = threadIdx.x;
    const int wave = t >> 6, lane = t & 63;

    if (t < 128) {
        int i = rowtile * 128 + t;
        swt[t] = (i < M) ? lwt[e * CAP + i] : 0.f;
    }

    const int row0 = offs[e] + rowtile * 128;
    const int r0 = t >> 2, k8 = t & 3;
    const int kofs = khalf * (FDIM / 2);
    const int sw0 = (k8 ^ ((r0 >> 1) & 3)) * 8;        // inverse-swizzled source chunk
    const unsigned short* pA0 = hbuf + (size_t)(row0 + r0) * FDIM + kofs + sw0;
    const unsigned short* pA1 = hbuf + (size_t)(row0 + 64 + r0) * FDIM + kofs + sw0;
    const size_t wb = (size_t)e * HDIM * FDIM + (size_t)(htile * 128) * FDIM;
    const unsigned short* pB0 = wdt + wb + (size_t)r0 * FDIM + kofs + sw0;
    const unsigned short* pB1 = wdt + wb + (size_t)(64 + r0) * FDIM + kofs + sw0;

    const int wm = wave >> 1, wn = wave & 1;
    const int fr = lane & 15, kg = lane >> 4;
    const int cswz = (kg ^ ((fr >> 1) & 3)) * 8;       // swizzled read chunk

    floatx4 acc[4][4];
#pragma unroll
    for (int mi = 0; mi < 4; ++mi)
#pragma unroll
        for (int ni = 0; ni < 4; ++ni) {
            floatx4 z = {0.f, 0.f, 0.f, 0.f};
            acc[mi][ni] = z;
        }

    auto stage = [&](int b) {
        gl2lds16(pA0, &lA[b][wave * 512]);        pA0 += 32;
        gl2lds16(pA1, &lA[b][2048 + wave * 512]); pA1 += 32;
        gl2lds16(pB0, &lB[b][wave * 512]);        pB0 += 32;
        gl2lds16(pB1, &lB[b][2048 + wave * 512]); pB1 += 32;
    };
    auto compute = [&](int b) {
        short8 a[4], bb[4];
#pragma unroll
        for (int mi = 0; mi < 4; ++mi)
            a[mi] = *(const short8*)&lA[b][(wm * 64 + mi * 16 + fr) * 32 + cswz];
#pragma unroll
        for (int ni = 0; ni < 4; ++ni)
            bb[ni] = *(const short8*)&lB[b][(wn * 64 + ni * 16 + fr) * 32 + cswz];
#pragma unroll
        for (int mi = 0; mi < 4; ++mi)
#pragma unroll
            for (int ni = 0; ni < 4; ++ni)
                acc[mi][ni] = __builtin_amdgcn_mfma_f32_16x16x32_bf16(a[mi], bb[ni], acc[mi][ni], 0, 0, 0);
    };

    // 64 K-steps of BK=32 over this K-half, double-buffered, stage-ahead by 1
    stage(0);
    __syncthreads();
#pragma unroll 1
    for (int it = 0; it < 32; ++it) {
        stage(1);
        compute(0);
        __syncthreads();
        if (it < 31) stage(0);
        compute(1);
        __syncthreads();
    }

    float* ob = obuf + (size_t)khalf * OBR * HDIM;
#pragma unroll
    for (int mi = 0; mi < 4; ++mi)
#pragma unroll
        for (int ni = 0; ni < 4; ++ni) {
            int c = htile * 128 + wn * 64 + ni * 16 + fr;
#pragma unroll
            for (int r = 0; r < 4; ++r) {
                int rr = wm * 64 + mi * 16 + kg * 4 + r;
                if (rowtile * 128 + rr < M)
                    ob[(size_t)(row0 + rr) * HDIM + c] = acc[mi][ni][r] * swt[rr];
            }
        }
}

// ---------------- combine: out[tok] = sum over 2 slots x 2 k-halves ----------------
__global__ void k_combine(const float* __restrict__ obuf, const int* __restrict__ tslot,
                          const int* __restrict__ offs, float* __restrict__ out) {
    int gid = blockIdx.x * 256 + threadIdx.x;
    int tok = gid >> 8;           // 256 threads per token
    int c = (gid & 255) * 4;
    int s0 = tslot[tok * 2], s1 = tslot[tok * 2 + 1];
    size_t r0 = (size_t)(offs[s0 >> 16] + (s0 & 0xFFFF));
    size_t r1 = (size_t)(offs[s1 >> 16] + (s1 & 0xFFFF));
    float4v v00 = *(const float4v*)(obuf + r0 * HDIM + c);
    float4v v01 = *(const float4v*)(obuf + ((size_t)OBR + r0) * HDIM + c);
    float4v v10 = *(const float4v*)(obuf + r1 * HDIM + c);
    float4v v11 = *(const float4v*)(obuf + ((size_t)OBR + r1) * HDIM + c);
    float4v s = v00 + v01 + v10 + v11;
    *(float4v*)(out + (size_t)tok * HDIM + c) = s;
}

extern "C" void kernel_launch(void* const* d_in, const int* in_sizes, int n_in,
                              void* d_out, int out_size, void* d_ws, size_t ws_size,
                              hipStream_t stream) {
    const float* x     = (const float*)d_in[0];  // [4096][1024]
    const float* wgate = (const float*)d_in[1];  // [1024][8]
    const float* wg    = (const float*)d_in[2];  // [8][1024][4096]
    const float* wu    = (const float*)d_in[3];  // [8][1024][4096]
    const float* wd    = (const float*)d_in[4];  // [8][4096][1024]
    float* out = (float*)d_out;

    char* ws = (char*)d_ws;
    size_t off = 0;
    unsigned short* xb  = (unsigned short*)(ws + off); off += (size_t)T_TOK * HDIM * 2;
    unsigned short* wgt = (unsigned short*)(ws + off); off += (size_t)NEXP * FDIM * HDIM * 2;
    unsigned short* wut = (unsigned short*)(ws + off); off += (size_t)NEXP * FDIM * HDIM * 2;
    unsigned short* wdt = (unsigned short*)(ws + off); off += (size_t)NEXP * HDIM * FDIM * 2;
    unsigned short* hbuf= (unsigned short*)(ws + off); off += (size_t)OBR * FDIM * 2;
    int*   ltok   = (int*)(ws + off);   off += (size_t)NEXP * CAP * 4;
    float* lwt    = (float*)(ws + off); off += (size_t)NEXP * CAP * 4;
    int*   tslot  = (int*)(ws + off);   off += (size_t)T_TOK * 2 * 4;
    int*   counts = (int*)(ws + off);   off += 256;
    int*   offs   = (int*)(ws + off);   off += 256;
    int*   wl     = (int*)(ws + off);   off += MAXWL * 4;
    int*   nwl    = (int*)(ws + off);   off += 256;
    // obuf aliases wgt+wut (dead after gemm1): 2*OBR*HDIM*4 = 68 MB < 134 MB
    float* obuf = (float*)wgt;

    hipMemsetAsync(counts, 0, 32, stream);

    k_router<<<T_TOK / 4, 256, 0, stream>>>(x, wgate, xb, counts, ltok, lwt, tslot);
    k_transpose_cast2<<<dim3(FDIM / 64, HDIM / 64, 16), 256, 0, stream>>>(wg, wu, wgt, wut);
    k_transpose_cast<<<dim3(HDIM / 64, FDIM / 64, NEXP), 256, 0, stream>>>(wd, wdt, FDIM, HDIM);
    k_prefix<<<1, 64, 0, stream>>>(counts, offs, wl, nwl);
    k_gemm1<<<8 * 8 * 72, 256, 0, stream>>>(xb, wgt, wut, counts, offs, ltok, wl, nwl, hbuf);
    k_gemm2<<<8 * 2 * 72, 256, 0, stream>>>(hbuf, wdt, counts, offs, lwt, wl, nwl, obuf);
    k_combine<<<T_TOK * HDIM / 1024, 256, 0, stream>>>(obuf, tslot, offs, out);
}